// Round 14
// baseline (59.332 us; speedup 1.0000x reference)
//
#include <hip/hip_runtime.h>
#include <math.h>

// TopK router via MFMA: logits = x @ W^T + b ; top-2 over E=64 ; sparse softmax.
// x: [T=16384, D=2048] f32, W: [64, 2048] f32, b: [64] f32.
// d_out: [T*64] router probs f32, then [T*2] top-k indices as f32.
//
// R14: barrier-free main loop. R12/R13 plateaued at ~55 us with ALL pipes
// < 25% -- the per-chunk stage->barrier->compute convoy is the binding
// constraint (grid caps blocks/CU at 4, so barrier gaps can't be filled).
// Fix: each wave owns 16 tokens x ALL 64 experts x one K-quarter. A-frags
// are loaded per-lane directly from global (lane = its own 8-float frag
// rows) and converted in-register -> NO LDS, NO barriers in the main loop.
// x still read exactly once; cvt total unchanged; B from L2-resident WB.
// Cross-wave combine: one f32-partial LDS exchange + one barrier at end.
// Numerics bit-identical to R13 (absmax 0): same f2b splits, same 6-MFMA
// order, same 96-accumulate fp32 chains per K-quarter, f64 merge order
// ((p0+p1)+p2)+p3 == R13's sequential acc64 merge.
// Spill sentinel: WRITE_SIZE ~4.2 MB; VGPR est ~110 (cap 128 via LB(256,4)).

#define RD 2048
#define RE 64
#define TB 16                    // tokens per block (= MFMA tile rows)
#define NCQ 8                    // chunks (64 k) per K-quarter

typedef __attribute__((ext_vector_type(8))) short bf16x8;
typedef __attribute__((ext_vector_type(4))) float f32x4;
typedef __attribute__((ext_vector_type(4))) unsigned int u32x4;

__device__ __forceinline__ unsigned short f2b(float f) {  // RNE f32->bf16 bits
    unsigned int u = __float_as_uint(f);
    unsigned int r = ((u >> 16) & 1u) + 0x7fffu;
    return (unsigned short)((u + r) >> 16);
}
__device__ __forceinline__ float b2f(unsigned short h) {
    return __uint_as_float(((unsigned int)h) << 16);
}

// split 8 floats (two f32x4, consecutive k) -> packed bf16 h/l/l2, 4 dwords each
__device__ __forceinline__ void cvt8(const f32x4 a, const f32x4 bq,
                                     unsigned int* h, unsigned int* l,
                                     unsigned int* l2) {
    float v[8] = {a.x, a.y, a.z, a.w, bq.x, bq.y, bq.z, bq.w};
#pragma unroll
    for (int j = 0; j < 4; ++j) {
        const float a0 = v[2 * j], a1 = v[2 * j + 1];
        const unsigned short h0 = f2b(a0); const float r0 = a0 - b2f(h0);
        const unsigned short h1 = f2b(a1); const float r1 = a1 - b2f(h1);
        const unsigned short m0 = f2b(r0); const float s0 = r0 - b2f(m0);
        const unsigned short m1 = f2b(r1); const float s1 = r1 - b2f(m1);
        const unsigned short q0 = f2b(s0);
        const unsigned short q1 = f2b(s1);
        h[j]  = (unsigned int)h0 | ((unsigned int)h1 << 16);
        l[j]  = (unsigned int)m0 | ((unsigned int)m1 << 16);
        l2[j] = (unsigned int)q0 | ((unsigned int)q1 << 16);
    }
}

// ---------- prep: W -> 3-way bf16 B-fragments (identical to R10-R13) ----------
// WB dword layout: ((ks*4 + et)*3 + comp)*256 + lane*4   (64 ks total)
__global__ __launch_bounds__(256) void wprep_kernel(
    const float* __restrict__ W, unsigned int* __restrict__ WB)
{
    const int ks = blockIdx.x;            // 0..63
    const int et = threadIdx.x >> 6;      // 0..3
    const int lane = threadIdx.x & 63;
    const int e = et * 16 + (lane & 15);
    const int k0 = ks * 32 + (lane >> 4) * 8;
    const float* src = W + (size_t)e * RD + k0;
    const f32x4 a = *(const f32x4*)(src);
    const f32x4 bq = *(const f32x4*)(src + 4);
    unsigned int h[4], l[4], l2[4];
    cvt8(a, bq, h, l, l2);
    unsigned int* dst = WB + (size_t)((ks * 4 + et) * 3) * 256 + lane * 4;
    *(u32x4*)(dst)       = *(u32x4*)h;
    *(u32x4*)(dst + 256) = *(u32x4*)l;
    *(u32x4*)(dst + 512) = *(u32x4*)l2;
}

// 6-product MFMA group (order identical to R10-R13)
#define SIXMFMA(AH, AL, AQ, ACC, WP) do {                                  \
    const bf16x8 Bh_ = *(const bf16x8*)(WP);                               \
    const bf16x8 Bl_ = *(const bf16x8*)((WP) + 256);                       \
    const bf16x8 Bq_ = *(const bf16x8*)((WP) + 512);                       \
    ACC = __builtin_amdgcn_mfma_f32_16x16x32_bf16(AH, Bh_, ACC, 0, 0, 0);  \
    ACC = __builtin_amdgcn_mfma_f32_16x16x32_bf16(AH, Bl_, ACC, 0, 0, 0);  \
    ACC = __builtin_amdgcn_mfma_f32_16x16x32_bf16(AL, Bh_, ACC, 0, 0, 0);  \
    ACC = __builtin_amdgcn_mfma_f32_16x16x32_bf16(AL, Bl_, ACC, 0, 0, 0);  \
    ACC = __builtin_amdgcn_mfma_f32_16x16x32_bf16(AH, Bq_, ACC, 0, 0, 0);  \
    ACC = __builtin_amdgcn_mfma_f32_16x16x32_bf16(AQ, Bh_, ACC, 0, 0, 0);  \
} while (0)

// ---------- main ----------
__global__ __launch_bounds__(256, 4) void topk_router_kernel(
    const float* __restrict__ x,
    const unsigned int* __restrict__ WB,
    const float* __restrict__ b,
    float* __restrict__ out_router,
    float* __restrict__ out_idx,
    int total_tokens)
{
    const int tid = threadIdx.x;
    const int lane = tid & 63;
    const int wq = __builtin_amdgcn_readfirstlane(tid >> 6);  // K-quarter 0..3
    const int tok0 = blockIdx.x * TB;

    __shared__ __align__(16) float PS[4][TB][68];   // f32 partials, 17.4 KB

    // per-lane A addressing: row = its token, cols = its frag k-range
    const int tmax = total_tokens - 1;
    const int row = min(tok0 + (lane & 15), tmax);
    const float* ga = x + (size_t)row * RD + wq * (RD / 4) + (lane >> 4) * 8;

    f32x4 acc0 = {0.f, 0.f, 0.f, 0.f};
    f32x4 acc1 = {0.f, 0.f, 0.f, 0.f};
    f32x4 acc2 = {0.f, 0.f, 0.f, 0.f};
    f32x4 acc3 = {0.f, 0.f, 0.f, 0.f};

    // prologue: load chunk 0's 16 floats (2 ksteps x 8)
    f32x4 p0 = *(const f32x4*)(ga + 0);
    f32x4 p1 = *(const f32x4*)(ga + 4);
    f32x4 p2 = *(const f32x4*)(ga + 32);
    f32x4 p3 = *(const f32x4*)(ga + 36);

#pragma unroll 1
    for (int c = 0; c < NCQ; ++c) {
        // issue chunk c+1's loads early (no barrier to wait behind)
        const int cn = (c + 1 < NCQ) ? (c + 1) : 0;
        const float* gn = ga + (size_t)cn * 64;
        const f32x4 n0 = *(const f32x4*)(gn + 0);
        const f32x4 n1 = *(const f32x4*)(gn + 4);
        const f32x4 n2 = *(const f32x4*)(gn + 32);
        const f32x4 n3 = *(const f32x4*)(gn + 36);

        // in-register 3-way split for both ksteps
        unsigned int h0[4], l0[4], q0[4], h1[4], l1[4], q1[4];
        cvt8(p0, p1, h0, l0, q0);
        cvt8(p2, p3, h1, l1, q1);
        const bf16x8 A0h = *(const bf16x8*)h0;
        const bf16x8 A0l = *(const bf16x8*)l0;
        const bf16x8 A0q = *(const bf16x8*)q0;
        const bf16x8 A1h = *(const bf16x8*)h1;
        const bf16x8 A1l = *(const bf16x8*)l1;
        const bf16x8 A1q = *(const bf16x8*)q1;

        // B pointers: ksg = wq*16 + c*2 + ks
        const int ksg0 = wq * 16 + c * 2;
        const unsigned int* wp00 = WB + (size_t)((ksg0 * 4 + 0) * 3) * 256 + lane * 4;
        const unsigned int* wp01 = WB + (size_t)((ksg0 * 4 + 1) * 3) * 256 + lane * 4;
        const unsigned int* wp02 = WB + (size_t)((ksg0 * 4 + 2) * 3) * 256 + lane * 4;
        const unsigned int* wp03 = WB + (size_t)((ksg0 * 4 + 3) * 3) * 256 + lane * 4;
        SIXMFMA(A0h, A0l, A0q, acc0, wp00);
        SIXMFMA(A0h, A0l, A0q, acc1, wp01);
        SIXMFMA(A0h, A0l, A0q, acc2, wp02);
        SIXMFMA(A0h, A0l, A0q, acc3, wp03);

        const int ksg1 = ksg0 + 1;
        const unsigned int* wp10 = WB + (size_t)((ksg1 * 4 + 0) * 3) * 256 + lane * 4;
        const unsigned int* wp11 = WB + (size_t)((ksg1 * 4 + 1) * 3) * 256 + lane * 4;
        const unsigned int* wp12 = WB + (size_t)((ksg1 * 4 + 2) * 3) * 256 + lane * 4;
        const unsigned int* wp13 = WB + (size_t)((ksg1 * 4 + 3) * 3) * 256 + lane * 4;
        SIXMFMA(A1h, A1l, A1q, acc0, wp10);
        SIXMFMA(A1h, A1l, A1q, acc1, wp11);
        SIXMFMA(A1h, A1l, A1q, acc2, wp12);
        SIXMFMA(A1h, A1l, A1q, acc3, wp13);

        p0 = n0; p1 = n1; p2 = n2; p3 = n3;
    }

    // ---- f32 partials -> LDS (only cross-wave step) ----
#pragma unroll
    for (int r = 0; r < 4; ++r) {
        const int t = (lane >> 4) * 4 + r;                 // C/D row = token
        PS[wq][t][0 * 16 + (lane & 15)] = acc0[r];
        PS[wq][t][1 * 16 + (lane & 15)] = acc1[r];
        PS[wq][t][2 * 16 + (lane & 15)] = acc2[r];
        PS[wq][t][3 * 16 + (lane & 15)] = acc3[r];
    }
    __syncthreads();

    const double bias = (double)b[lane];

    // epilogue (R5-verified): wave wq handles tokens [wq*4, wq*4+4)
#pragma unroll 1
    for (int i = 0; i < 4; ++i) {
        const int t = wq * 4 + i;
        const int token = tok0 + t;
        // f64 merge order identical to R13: ((p0+p1)+p2)+p3 then +bias
        const double v = (double)PS[0][t][lane] + (double)PS[1][t][lane]
                       + (double)PS[2][t][lane] + (double)PS[3][t][lane] + bias;

        // argmax #1 (value desc, tie -> lower lane)
        double bestv = v;
        int besti = lane;
#pragma unroll
        for (int off = 32; off > 0; off >>= 1) {
            double ov = __shfl_xor(bestv, off, 64);
            int oi = __shfl_xor(besti, off, 64);
            if (ov > bestv || (ov == bestv && oi < besti)) { bestv = ov; besti = oi; }
        }

        // argmax #2 excluding winner
        double v2 = (lane == besti) ? -INFINITY : v;
        double best2v = v2;
        int best2i = lane;
#pragma unroll
        for (int off = 32; off > 0; off >>= 1) {
            double ov = __shfl_xor(best2v, off, 64);
            int oi = __shfl_xor(best2i, off, 64);
            if (ov > best2v || (ov == best2v && oi < best2i)) { best2v = ov; best2i = oi; }
        }

        // 2-element softmax; all other experts exactly 0
        const float e2 = expf((float)(best2v - bestv));
        const float denom = 1.0f + e2;
        const float p1v = 1.0f / denom;
        const float p2v = e2 / denom;

        if (token < total_tokens) {
            float outv = 0.0f;
            if (lane == besti) outv = p1v;
            else if (lane == best2i) outv = p2v;
            out_router[(size_t)token * RE + lane] = outv;
            if (lane == 0) {
                out_idx[(size_t)token * 2 + 0] = (float)besti;
                out_idx[(size_t)token * 2 + 1] = (float)best2i;
            }
        }
    }
}

extern "C" void kernel_launch(void* const* d_in, const int* in_sizes, int n_in,
                              void* d_out, int out_size, void* d_ws, size_t ws_size,
                              hipStream_t stream) {
    const float* x = (const float*)d_in[0];
    const float* W = (const float*)d_in[1];
    const float* b = (const float*)d_in[2];

    const int E = in_sizes[2];                 // 64
    const int D = in_sizes[1] / E;             // 2048
    const int T = in_sizes[0] / D;             // 16384
    (void)E; (void)D;

    unsigned int* WB = (unsigned int*)d_ws;    // 64*4*3*1024 B = 768 KB
    float* out_router = (float*)d_out;
    float* out_idx = out_router + (size_t)T * RE;

    wprep_kernel<<<64, 256, 0, stream>>>(W, WB);

    const int grid = (T + TB - 1) / TB;        // 1024
    topk_router_kernel<<<grid, 256, 0, stream>>>(x, WB, b, out_router, out_idx, T);
}

// Round 15
// 58.520 us; speedup vs baseline: 1.0139x; 1.0139x over previous
//
#include <hip/hip_runtime.h>
#include <math.h>

// TopK router via MFMA: logits = x @ W^T + b ; top-2 over E=64 ; sparse softmax.
// x: [T=16384, D=2048] f32, W: [64, 2048] f32, b: [64] f32.
// d_out: [T*64] router probs f32, then [T*2] top-k indices as f32.
//
// R15: B-traffic amortization. R12-R14 all plateau at ~55 us with every
// pipe < 25% and identical WB re-read traffic (1024 blocks x 768 KB =
// 786 MB from L2 ~ 23-45 us) -- the hidden binder. Now TB=32: each wave
// (one K-quarter) computes TWO token-tiles, loading each B triple ONCE
// into registers and feeding both tiles -> B L2 traffic halved (393 MB).
// Grid 512, 2 blocks/CU, 8 waves/CU (R12 proved occupancy isn't the
// binder; per-wave ILP doubles). launch_bounds(256,2): 256-VGPR cap, no
// squeeze. Numerics bit-identical to R14 (absmax 0): same f2b splits,
// same per-acc 6-MFMA order, same 96-accumulate chains (merge at c==7),
// same ((p0+p1)+p2)+p3 f64 merge.
// Spill sentinel: WRITE_SIZE ~4.2 MB.

#define RD 2048
#define RE 64
#define TB 32                    // tokens per block (2 tiles of 16)
#define NCQ 8                    // chunks (64 k) per K-quarter

typedef __attribute__((ext_vector_type(8))) short bf16x8;
typedef __attribute__((ext_vector_type(4))) float f32x4;
typedef __attribute__((ext_vector_type(4))) unsigned int u32x4;

__device__ __forceinline__ unsigned short f2b(float f) {  // RNE f32->bf16 bits
    unsigned int u = __float_as_uint(f);
    unsigned int r = ((u >> 16) & 1u) + 0x7fffu;
    return (unsigned short)((u + r) >> 16);
}
__device__ __forceinline__ float b2f(unsigned short h) {
    return __uint_as_float(((unsigned int)h) << 16);
}

// split 8 floats (two f32x4, consecutive k) -> packed bf16 h/l/l2, 4 dwords each
__device__ __forceinline__ void cvt8(const f32x4 a, const f32x4 bq,
                                     unsigned int* h, unsigned int* l,
                                     unsigned int* l2) {
    float v[8] = {a.x, a.y, a.z, a.w, bq.x, bq.y, bq.z, bq.w};
#pragma unroll
    for (int j = 0; j < 4; ++j) {
        const float a0 = v[2 * j], a1 = v[2 * j + 1];
        const unsigned short h0 = f2b(a0); const float r0 = a0 - b2f(h0);
        const unsigned short h1 = f2b(a1); const float r1 = a1 - b2f(h1);
        const unsigned short m0 = f2b(r0); const float s0 = r0 - b2f(m0);
        const unsigned short m1 = f2b(r1); const float s1 = r1 - b2f(m1);
        const unsigned short q0 = f2b(s0);
        const unsigned short q1 = f2b(s1);
        h[j]  = (unsigned int)h0 | ((unsigned int)h1 << 16);
        l[j]  = (unsigned int)m0 | ((unsigned int)m1 << 16);
        l2[j] = (unsigned int)q0 | ((unsigned int)q1 << 16);
    }
}

// ---------- prep: W -> 3-way bf16 B-fragments (identical to R10-R14) ----------
// WB dword layout: ((ks*4 + et)*3 + comp)*256 + lane*4   (64 ks total)
__global__ __launch_bounds__(256) void wprep_kernel(
    const float* __restrict__ W, unsigned int* __restrict__ WB)
{
    const int ks = blockIdx.x;            // 0..63
    const int et = threadIdx.x >> 6;      // 0..3
    const int lane = threadIdx.x & 63;
    const int e = et * 16 + (lane & 15);
    const int k0 = ks * 32 + (lane >> 4) * 8;
    const float* src = W + (size_t)e * RD + k0;
    const f32x4 a = *(const f32x4*)(src);
    const f32x4 bq = *(const f32x4*)(src + 4);
    unsigned int h[4], l[4], l2[4];
    cvt8(a, bq, h, l, l2);
    unsigned int* dst = WB + (size_t)((ks * 4 + et) * 3) * 256 + lane * 4;
    *(u32x4*)(dst)       = *(u32x4*)h;
    *(u32x4*)(dst + 256) = *(u32x4*)l;
    *(u32x4*)(dst + 512) = *(u32x4*)l2;
}

// Load one B triple, feed TWO accumulators (token tiles) -- 12 MFMAs.
// Per-acc product order identical to R10-R14: hh, hl, lh, ll, hq, qh.
#define TWELVE(AH0, AL0, AQ0, AH1, AL1, AQ1, ACC0, ACC1, WP) do {          \
    const bf16x8 Bh_ = *(const bf16x8*)(WP);                               \
    const bf16x8 Bl_ = *(const bf16x8*)((WP) + 256);                       \
    const bf16x8 Bq_ = *(const bf16x8*)((WP) + 512);                       \
    ACC0 = __builtin_amdgcn_mfma_f32_16x16x32_bf16(AH0, Bh_, ACC0, 0, 0, 0); \
    ACC0 = __builtin_amdgcn_mfma_f32_16x16x32_bf16(AH0, Bl_, ACC0, 0, 0, 0); \
    ACC0 = __builtin_amdgcn_mfma_f32_16x16x32_bf16(AL0, Bh_, ACC0, 0, 0, 0); \
    ACC0 = __builtin_amdgcn_mfma_f32_16x16x32_bf16(AL0, Bl_, ACC0, 0, 0, 0); \
    ACC0 = __builtin_amdgcn_mfma_f32_16x16x32_bf16(AH0, Bq_, ACC0, 0, 0, 0); \
    ACC0 = __builtin_amdgcn_mfma_f32_16x16x32_bf16(AQ0, Bh_, ACC0, 0, 0, 0); \
    ACC1 = __builtin_amdgcn_mfma_f32_16x16x32_bf16(AH1, Bh_, ACC1, 0, 0, 0); \
    ACC1 = __builtin_amdgcn_mfma_f32_16x16x32_bf16(AH1, Bl_, ACC1, 0, 0, 0); \
    ACC1 = __builtin_amdgcn_mfma_f32_16x16x32_bf16(AL1, Bh_, ACC1, 0, 0, 0); \
    ACC1 = __builtin_amdgcn_mfma_f32_16x16x32_bf16(AL1, Bl_, ACC1, 0, 0, 0); \
    ACC1 = __builtin_amdgcn_mfma_f32_16x16x32_bf16(AH1, Bq_, ACC1, 0, 0, 0); \
    ACC1 = __builtin_amdgcn_mfma_f32_16x16x32_bf16(AQ1, Bh_, ACC1, 0, 0, 0); \
} while (0)

// ---------- main ----------
__global__ __launch_bounds__(256, 2) void topk_router_kernel(
    const float* __restrict__ x,
    const unsigned int* __restrict__ WB,
    const float* __restrict__ b,
    float* __restrict__ out_router,
    float* __restrict__ out_idx,
    int total_tokens)
{
    const int tid = threadIdx.x;
    const int lane = tid & 63;
    const int wq = __builtin_amdgcn_readfirstlane(tid >> 6);  // K-quarter 0..3
    const int tok0 = blockIdx.x * TB;

    __shared__ __align__(16) float PS[4][TB][68];   // f32 partials, 34.8 KB

    // per-lane A addressing: tile 0 rows tok0+[0,16), tile 1 rows tok0+[16,32)
    const int tmax = total_tokens - 1;
    const int row0 = min(tok0 + (lane & 15), tmax);
    const int row1 = min(tok0 + 16 + (lane & 15), tmax);
    const float* ga0 = x + (size_t)row0 * RD + wq * (RD / 4) + (lane >> 4) * 8;
    const float* ga1 = x + (size_t)row1 * RD + wq * (RD / 4) + (lane >> 4) * 8;

    f32x4 aA0 = {0.f,0.f,0.f,0.f}, aA1 = {0.f,0.f,0.f,0.f};
    f32x4 aA2 = {0.f,0.f,0.f,0.f}, aA3 = {0.f,0.f,0.f,0.f};
    f32x4 aB0 = {0.f,0.f,0.f,0.f}, aB1 = {0.f,0.f,0.f,0.f};
    f32x4 aB2 = {0.f,0.f,0.f,0.f}, aB3 = {0.f,0.f,0.f,0.f};

    // prologue: load chunk 0 (2 ksteps x 8 floats, both tiles)
    f32x4 p00 = *(const f32x4*)(ga0 + 0);
    f32x4 p01 = *(const f32x4*)(ga0 + 4);
    f32x4 p02 = *(const f32x4*)(ga0 + 32);
    f32x4 p03 = *(const f32x4*)(ga0 + 36);
    f32x4 p10 = *(const f32x4*)(ga1 + 0);
    f32x4 p11 = *(const f32x4*)(ga1 + 4);
    f32x4 p12 = *(const f32x4*)(ga1 + 32);
    f32x4 p13 = *(const f32x4*)(ga1 + 36);

    double acc64A[4] = {0.0, 0.0, 0.0, 0.0};
    double acc64B[4] = {0.0, 0.0, 0.0, 0.0};

#pragma unroll 1
    for (int c = 0; c < NCQ; ++c) {
        // issue chunk c+1's loads early (no barriers anywhere in the loop)
        const int cn = (c + 1 < NCQ) ? (c + 1) : 0;
        const float* g0n = ga0 + (size_t)cn * 64;
        const float* g1n = ga1 + (size_t)cn * 64;
        const f32x4 n00 = *(const f32x4*)(g0n + 0);
        const f32x4 n01 = *(const f32x4*)(g0n + 4);
        const f32x4 n02 = *(const f32x4*)(g0n + 32);
        const f32x4 n03 = *(const f32x4*)(g0n + 36);
        const f32x4 n10 = *(const f32x4*)(g1n + 0);
        const f32x4 n11 = *(const f32x4*)(g1n + 4);
        const f32x4 n12 = *(const f32x4*)(g1n + 32);
        const f32x4 n13 = *(const f32x4*)(g1n + 36);

        // in-register 3-way split: tile0/tile1 x kstep0/kstep1
        unsigned int h00[4], l00[4], q00[4], h01[4], l01[4], q01[4];
        unsigned int h10[4], l10[4], q10[4], h11[4], l11[4], q11[4];
        cvt8(p00, p01, h00, l00, q00);
        cvt8(p02, p03, h01, l01, q01);
        cvt8(p10, p11, h10, l10, q10);
        cvt8(p12, p13, h11, l11, q11);
        const bf16x8 A00h = *(const bf16x8*)h00, A00l = *(const bf16x8*)l00,
                     A00q = *(const bf16x8*)q00;
        const bf16x8 A01h = *(const bf16x8*)h01, A01l = *(const bf16x8*)l01,
                     A01q = *(const bf16x8*)q01;
        const bf16x8 A10h = *(const bf16x8*)h10, A10l = *(const bf16x8*)l10,
                     A10q = *(const bf16x8*)q10;
        const bf16x8 A11h = *(const bf16x8*)h11, A11l = *(const bf16x8*)l11,
                     A11q = *(const bf16x8*)q11;

        // kstep 0: B loaded once per etile, feeds both token tiles
        const int ksg0 = wq * 16 + c * 2;
        const unsigned int* w0 = WB + (size_t)(ksg0 * 4 * 3) * 256 + lane * 4;
        TWELVE(A00h, A00l, A00q, A10h, A10l, A10q, aA0, aB0, w0 + 0 * 768);
        TWELVE(A00h, A00l, A00q, A10h, A10l, A10q, aA1, aB1, w0 + 1 * 768);
        TWELVE(A00h, A00l, A00q, A10h, A10l, A10q, aA2, aB2, w0 + 2 * 768);
        TWELVE(A00h, A00l, A00q, A10h, A10l, A10q, aA3, aB3, w0 + 3 * 768);

        // kstep 1
        const unsigned int* w1 = w0 + 4 * 768;
        TWELVE(A01h, A01l, A01q, A11h, A11l, A11q, aA0, aB0, w1 + 0 * 768);
        TWELVE(A01h, A01l, A01q, A11h, A11l, A11q, aA1, aB1, w1 + 1 * 768);
        TWELVE(A01h, A01l, A01q, A11h, A11l, A11q, aA2, aB2, w1 + 2 * 768);
        TWELVE(A01h, A01l, A01q, A11h, A11l, A11q, aA3, aB3, w1 + 3 * 768);

        // f64 partial merge every 8 chunks (here: once, at c==7) --
        // chain length 96 accumulates, identical to R10-R14
        if ((c & 7) == 7) {
            acc64A[0] += (double)aA0.x; acc64A[1] += (double)aA0.y;
            acc64A[2] += (double)aA0.z; acc64A[3] += (double)aA0.w;
            acc64B[0] += (double)aB0.x; acc64B[1] += (double)aB0.y;
            acc64B[2] += (double)aB0.z; acc64B[3] += (double)aB0.w;
            // note: only acc*0 merged here; acc*1..3 merged below at write
        }

        p00 = n00; p01 = n01; p02 = n02; p03 = n03;
        p10 = n10; p11 = n11; p12 = n12; p13 = n13;
    }

    // ---- f32 partials -> LDS (only cross-wave step) ----
    // (acc*1..3 had exactly one 96-chain; their f64 merge is the cast here,
    //  same value as acc64 path since initial acc64 was 0)
#pragma unroll
    for (int r = 0; r < 4; ++r) {
        const int t = (lane >> 4) * 4 + r;                 // C/D row = token
        PS[wq][t][0 * 16 + (lane & 15)] = (float)acc64A[r];
        PS[wq][t][1 * 16 + (lane & 15)] = aA1[r];
        PS[wq][t][2 * 16 + (lane & 15)] = aA2[r];
        PS[wq][t][3 * 16 + (lane & 15)] = aA3[r];
        PS[wq][16 + t][0 * 16 + (lane & 15)] = (float)acc64B[r];
        PS[wq][16 + t][1 * 16 + (lane & 15)] = aB1[r];
        PS[wq][16 + t][2 * 16 + (lane & 15)] = aB2[r];
        PS[wq][16 + t][3 * 16 + (lane & 15)] = aB3[r];
    }
    __syncthreads();

    const double bias = (double)b[lane];

    // epilogue (R5-verified): wave wq handles tokens [wq*8, wq*8+8)
#pragma unroll 1
    for (int i = 0; i < 8; ++i) {
        const int t = wq * 8 + i;
        const int token = tok0 + t;
        // f64 merge order identical to R14: ((p0+p1)+p2)+p3 then +bias
        const double v = (double)PS[0][t][lane] + (double)PS[1][t][lane]
                       + (double)PS[2][t][lane] + (double)PS[3][t][lane] + bias;

        // argmax #1 (value desc, tie -> lower lane)
        double bestv = v;
        int besti = lane;
#pragma unroll
        for (int off = 32; off > 0; off >>= 1) {
            double ov = __shfl_xor(bestv, off, 64);
            int oi = __shfl_xor(besti, off, 64);
            if (ov > bestv || (ov == bestv && oi < besti)) { bestv = ov; besti = oi; }
        }

        // argmax #2 excluding winner
        double v2 = (lane == besti) ? -INFINITY : v;
        double best2v = v2;
        int best2i = lane;
#pragma unroll
        for (int off = 32; off > 0; off >>= 1) {
            double ov = __shfl_xor(best2v, off, 64);
            int oi = __shfl_xor(best2i, off, 64);
            if (ov > best2v || (ov == best2v && oi < best2i)) { best2v = ov; best2i = oi; }
        }

        // 2-element softmax; all other experts exactly 0
        const float e2 = expf((float)(best2v - bestv));
        const float denom = 1.0f + e2;
        const float p1v = 1.0f / denom;
        const float p2v = e2 / denom;

        if (token < total_tokens) {
            float outv = 0.0f;
            if (lane == besti) outv = p1v;
            else if (lane == best2i) outv = p2v;
            out_router[(size_t)token * RE + lane] = outv;
            if (lane == 0) {
                out_idx[(size_t)token * 2 + 0] = (float)besti;
                out_idx[(size_t)token * 2 + 1] = (float)best2i;
            }
        }
    }
}

extern "C" void kernel_launch(void* const* d_in, const int* in_sizes, int n_in,
                              void* d_out, int out_size, void* d_ws, size_t ws_size,
                              hipStream_t stream) {
    const float* x = (const float*)d_in[0];
    const float* W = (const float*)d_in[1];
    const float* b = (const float*)d_in[2];

    const int E = in_sizes[2];                 // 64
    const int D = in_sizes[1] / E;             // 2048
    const int T = in_sizes[0] / D;             // 16384
    (void)E; (void)D;

    unsigned int* WB = (unsigned int*)d_ws;    // 64*4*3*1024 B = 768 KB
    float* out_router = (float*)d_out;
    float* out_idx = out_router + (size_t)T * RE;

    wprep_kernel<<<64, 256, 0, stream>>>(W, WB);

    const int grid = (T + TB - 1) / TB;        // 512
    topk_router_kernel<<<grid, 256, 0, stream>>>(x, WB, b, out_router, out_idx, T);
}